// Round 11
// baseline (110.584 us; speedup 1.0000x reference)
//
#include <hip/hip_runtime.h>
#include <stdint.h>

#define N_NODES 100000
#define N_ELEM4 50000          // nibble-packed element table: 4 bits/node
#define N_EDGES 3200000
#define N_ELEMS 10
#define N_PAIRS (N_ELEMS * N_ELEMS)

#define NB 256                 // node buckets
#define NPB 391                // nodes per bucket: 256*391 = 100096 >= 100000
#define SCAT_THREADS 1024      // 16 waves/block; 73.1 KB LDS -> 2 blocks/CU
#define NBLK 512               // scatter blocks
#define EPB 6256               // edges per block: 512*6256 = 3,203,072 >= 3.2M
#define NGROUPS (EPB / 4)      // 1564 float4-groups per block
#define NG4 (N_EDGES / 4)      // 800000 float4-groups total
#define PREP_BLOCKS 196        // 196*256 = 50176 >= 50000 node-pair bytes

// records[NB][NBLK][CAP], bucket-major; CAP=20 vs live bucket load lam~10.5
// (R11: 24->20; P(>20)~0.26% -> ~340 spills device-wide, exact via overflow;
// saves ~2.1 MB each way on the records round trip)
#define CAP 20
#define REC_PER_B (NBLK * CAP)        // 10240 uints per bucket
#define OVF_CAP 16384

// dynamic LDS layout for scatter (bytes)
#define L_ELEM  0                         // uint4  s_elem4[3125]   50000 B
#define L_TAB   50000                     // float4 s_tab[100]       1600 B (16B aligned)
#define L_CNT   (L_TAB + 1600)            // uint   s_cnt[NB]        1024 B
#define L_REC   (L_CNT + 1024)            // uint   s_rec[NB*CAP]   20480 B
#define LDS_BYTES (L_REC + NB * CAP * 4)  // = 73104 B; x2 = 146208 < 160 KiB/CU

// ---------------------------------------------------------------------------
// Prep (verbatim R5): per-node argmax nibble table, pair table, zero ovf.
// ---------------------------------------------------------------------------
__global__ __launch_bounds__(256) void prep_kernel(
    const float* __restrict__ node_attrs,
    const int* __restrict__ atomic_numbers,
    const float* __restrict__ covalent_radii,
    uint8_t* __restrict__ node_elem4,
    float4* __restrict__ pair_tab,
    unsigned int* __restrict__ ovf_cnt) {
  int i = blockIdx.x * 256 + threadIdx.x;   // byte index: nodes 2i, 2i+1

  if (blockIdx.x == 0) {
    if (threadIdx.x < N_PAIRS) {
      int t = threadIdx.x;
      int eu = t / N_ELEMS, ev = t % N_ELEMS;
      float Zuf = (float)atomic_numbers[eu];
      float Zvf = (float)atomic_numbers[ev];
      float a = 0.4543f * 0.529f / (powf(Zuf, 0.3f) + powf(Zvf, 0.3f));
      float rmax = covalent_radii[(int)Zuf] + covalent_radii[(int)Zvf];
      pair_tab[t] = make_float4(1.0f / a, 0.5f * 14.3996f * Zuf * Zvf,
                                rmax, 1.0f / rmax);
    }
    if (threadIdx.x == 0) *ovf_cnt = 0u;
  }

  if (i < N_ELEM4) {
    unsigned int packed = 0;
#pragma unroll
    for (int h = 0; h < 2; ++h) {
      int node = 2 * i + h;
      const float2* row = (const float2*)(node_attrs + (size_t)node * N_ELEMS);
      float best = -INFINITY;
      int bj = 0;
#pragma unroll
      for (int k = 0; k < 5; ++k) {
        float2 v = row[k];
        if (v.x > best) { best = v.x; bj = 2 * k; }
        if (v.y > best) { best = v.y; bj = 2 * k + 1; }
      }
      packed |= (unsigned int)bj << (h * 4);
    }
    node_elem4[i] = (uint8_t)packed;
  }
}

// ---------------------------------------------------------------------------
// Per-edge math (verified). envelope(p=6): 1 - 28r^6 + 48r^7 - 21r^8, masked
// x<r_max. Dead (~57%) edges -> exactly 0.0f; live values strictly positive.
// ---------------------------------------------------------------------------
__device__ __forceinline__ float edge_val(float xi, int u, int v,
                                          const uint8_t* s_elem4,
                                          const float4* s_tab) {
  int eu = (s_elem4[u >> 1] >> ((u & 1) * 4)) & 0xF;
  int ev = (s_elem4[v >> 1] >> ((v & 1) * 4)) & 0xF;
  float4 tb = s_tab[eu * N_ELEMS + ev];
  float roa = xi * tb.x;
  float phi = 0.1818f  * __expf(-3.2f    * roa)
            + 0.5099f  * __expf(-0.9423f * roa)
            + 0.2802f  * __expf(-0.4028f * roa)
            + 0.02817f * __expf(-0.2016f * roa);
  float val = tb.y * phi * __builtin_amdgcn_rcpf(xi);
  float r  = xi * tb.w;
  float r2 = r * r;
  float r6 = r2 * r2 * r2;
  float env = 1.0f - 28.0f * r6 + 48.0f * r6 * r - 21.0f * r6 * r2;
  return (xi < tb.z) ? val * env : 0.0f;
}

// ---------------------------------------------------------------------------
// Phase 2 (R24): R10 structure with LOAD-BEFORE-STAGE: the 6 global edge
// loads (HBM-cold every iteration -- the harness's 256 MiB poison fill
// sweeps the whole LLC) are issued FIRST, so their ~900cy latency hides
// under the 50 KB table staging; the staging __syncthreads (vmcnt(0) drain)
// collects both. Removes one serial memory phase per block.
// ---------------------------------------------------------------------------
__global__ __launch_bounds__(SCAT_THREADS, 8) void scatter_kernel(
    const float* __restrict__ x,
    const int* __restrict__ edge_index,      // [2, E]
    const uint8_t* __restrict__ node_elem4,
    const float4* __restrict__ pair_tab,
    unsigned int* __restrict__ records,      // [NB][NBLK][CAP]
    unsigned int* __restrict__ ovf_cnt,
    uint2* __restrict__ ovf) {
  extern __shared__ char smem[];
  uint4*        s_elem4_v = (uint4*)(smem + L_ELEM);
  float4*       s_tab     = (float4*)(smem + L_TAB);
  unsigned int* s_cnt     = (unsigned int*)(smem + L_CNT);
  unsigned int* s_rec     = (unsigned int*)(smem + L_REC);
  const uint8_t* s_elem4  = (const uint8_t*)s_elem4_v;

  int tid = threadIdx.x;

  // ---- issue edge loads FIRST (latency hides under staging) ----
  float4 xv[2];
  int4 uu[2], vv[2];
  bool okk[2];
#pragma unroll
  for (int k = 0; k < 2; ++k) {
    int gl = k * SCAT_THREADS + tid;          // local float4-group (< 2048)
    int g  = blockIdx.x * NGROUPS + gl;       // global float4-group
    okk[k] = (gl < NGROUPS) && (g < NG4);
    int gc = okk[k] ? g : (NG4 - 1);          // clamp: loads unconditional
    int e = gc * 4;
    xv[k] = *(const float4*)(x + e);
    uu[k] = *(const int4*)(edge_index + e);
    vv[k] = *(const int4*)(edge_index + N_EDGES + e);
  }

  // ---- stage packed element table (50 KB) + pair table ----
  {
    const uint4* src = (const uint4*)node_elem4;
    for (int j = tid; j < N_ELEM4 / 16; j += SCAT_THREADS) s_elem4_v[j] = src[j];
  }
  if (tid < N_PAIRS) s_tab[tid] = pair_tab[tid];
  if (tid < NB) s_cnt[tid] = 0u;
  __syncthreads();                            // drains staging AND edge loads

  float val[8];
  unsigned int bl[8];          // (bucket<<9) | localid  (b<256, lid<391)

  // ---- pass A: pure compute from registers + LDS ----
#pragma unroll
  for (int k = 0; k < 2; ++k) {
    int ru[4] = {uu[k].x, uu[k].y, uu[k].z, uu[k].w};
    int rv[4] = {vv[k].x, vv[k].y, vv[k].z, vv[k].w};
    float xs[4] = {xv[k].x, xv[k].y, xv[k].z, xv[k].w};
#pragma unroll
    for (int c = 0; c < 4; ++c) {
      int j = k * 4 + c;
      float v = edge_val(xs[c], ru[c], rv[c], s_elem4, s_tab);
      val[j] = okk[k] ? v : 0.0f;
      unsigned int b = (unsigned int)rv[c] / NPB;
      unsigned int lid = (unsigned int)rv[c] - b * NPB;
      bl[j] = (b << 9) | lid;
    }
  }

  // ---- pass B: commit (rank + ranked store; zero-skip kills ~57%) ----
#pragma unroll
  for (int j = 0; j < 8; ++j) {
    if (val[j] != 0.0f) {
      unsigned int b = bl[j] >> 9;
      unsigned int r = atomicAdd(&s_cnt[b], 1u);       // LDS rank (CU-local)
      if (r < CAP) {
        s_rec[b * CAP + r] = (__float_as_uint(val[j]) & ~0x1FFu) | (bl[j] & 0x1FFu);
      } else {                                         // ~340 device-wide
        unsigned int idx = atomicAdd(ovf_cnt, 1u);
        if (idx < OVF_CAP) {
          unsigned int node = b * NPB + (bl[j] & 0x1FFu);
          ovf[idx] = make_uint2(__float_as_uint(val[j]), node);
        }
      }
    }
  }
  __syncthreads();

  // coalesced dump: every (bucket,slot) written; empty slots = 0.
  for (int j = tid; j < NB * CAP; j += SCAT_THREADS) {
    int b = j / CAP, slot = j - b * CAP;
    unsigned int c = s_cnt[b]; if (c > CAP) c = CAP;
    unsigned int rec = ((unsigned int)slot < c) ? s_rec[j] : 0u;
    records[(size_t)b * REC_PER_B + (size_t)blockIdx.x * CAP + slot] = rec;
  }
}

// ---------------------------------------------------------------------------
// Phase 3: block b reads records[b] as ONE contiguous 40KB coalesced run of
// uint4 (4 recs/issue), skips rec==0, LDS float atomics into 391 bins,
// overflow list, coalesced store of every out element.
// ---------------------------------------------------------------------------
__global__ __launch_bounds__(1024) void reduce_kernel(
    const unsigned int* __restrict__ records,
    const unsigned int* __restrict__ ovf_cnt,
    const uint2* __restrict__ ovf,
    float* __restrict__ out) {
  __shared__ float bins[NPB];
  int b = blockIdx.x, tid = threadIdx.x;

  if (tid < NPB) bins[tid] = 0.0f;
  __syncthreads();

  const uint4* rp4 = (const uint4*)(records + (size_t)b * REC_PER_B);
  for (int i = tid; i < REC_PER_B / 4; i += 1024) {
    uint4 r4 = rp4[i];
    if (r4.x != 0u)
      atomicAdd(&bins[r4.x & 0x1FFu], __uint_as_float(r4.x & ~0x1FFu));
    if (r4.y != 0u)
      atomicAdd(&bins[r4.y & 0x1FFu], __uint_as_float(r4.y & ~0x1FFu));
    if (r4.z != 0u)
      atomicAdd(&bins[r4.z & 0x1FFu], __uint_as_float(r4.z & ~0x1FFu));
    if (r4.w != 0u)
      atomicAdd(&bins[r4.w & 0x1FFu], __uint_as_float(r4.w & ~0x1FFu));
  }

  unsigned int on = *ovf_cnt; if (on > OVF_CAP) on = OVF_CAP;
  for (unsigned int j = tid; j < on; j += 1024) {
    uint2 e2 = ovf[j];
    unsigned int nb = e2.y / NPB;
    if (nb == (unsigned int)b)
      atomicAdd(&bins[e2.y - nb * NPB], __uint_as_float(e2.x));
  }
  __syncthreads();

  int nb0 = b * NPB;
  if (tid < NPB && nb0 + tid < N_NODES) out[nb0 + tid] = bins[tid];
}

// ---------------------------------------------------------------------------
extern "C" void kernel_launch(void* const* d_in, const int* in_sizes, int n_in,
                              void* d_out, int out_size, void* d_ws, size_t ws_size,
                              hipStream_t stream) {
  const float* x              = (const float*)d_in[0];
  const float* node_attrs     = (const float*)d_in[1];
  const int*   edge_index     = (const int*)d_in[2];
  const int*   atomic_numbers = (const int*)d_in[3];
  const float* covalent_radii = (const float*)d_in[4];
  float* out = (float*)d_out;

  // ws layout (aligned sections):
  //   records    uint [NB*NBLK*CAP] = 10,485,760 B @ 0
  //   ovf_cnt    uint               =        16 B @ 10,485,760
  //   ovf        uint2[OVF_CAP]     =   131,072 B @ 10,485,776
  //   pair_tab   float4[100]        =     1,600 B @ 10,616,848
  //   node_elem4 uint8[N_ELEM4]     =    50,000 B @ 10,618,448
  char* wsp = (char*)d_ws;
  unsigned int* records    = (unsigned int*)wsp;
  unsigned int* ovf_cnt    = (unsigned int*)(wsp + 10485760);
  uint2*        ovf        = (uint2*)(wsp + 10485776);
  float4*       pair_tab   = (float4*)(wsp + 10616848);
  uint8_t*      node_elem4 = (uint8_t*)(wsp + 10618448);

  prep_kernel<<<PREP_BLOCKS, 256, 0, stream>>>(
      node_attrs, atomic_numbers, covalent_radii, node_elem4, pair_tab,
      ovf_cnt);

  scatter_kernel<<<NBLK, SCAT_THREADS, LDS_BYTES, stream>>>(
      x, edge_index, node_elem4, pair_tab, records, ovf_cnt, ovf);

  reduce_kernel<<<NB, 1024, 0, stream>>>(records, ovf_cnt, ovf, out);
}

// Round 12
// 104.218 us; speedup vs baseline: 1.0611x; 1.0611x over previous
//
#include <hip/hip_runtime.h>
#include <stdint.h>

#define N_NODES 100000
#define N_ELEM4 50000          // nibble-packed element table: 4 bits/node
#define N_EDGES 3200000
#define N_ELEMS 10
#define N_PAIRS (N_ELEMS * N_ELEMS)

#define NB 256                 // node buckets
#define NPB 391                // nodes per bucket: 256*391 = 100096 >= 100000
#define SCAT_THREADS 1024      // 16 waves/block; 77.2 KB LDS -> 2 blocks/CU
#define NBLK 512               // scatter blocks
#define EPB 6256               // edges per block: 512*6256 = 3,203,072 >= 3.2M
#define NGROUPS (EPB / 4)      // 1564 float4-groups per block
#define NG4 (N_EDGES / 4)      // 800000 float4-groups total
#define PREP_BLOCKS 196        // 196*256 = 50176 >= 50000 node-pair bytes

// Fixed-capacity record slots: records[NB][NBLK][CAP], bucket-major so the
// reduce reads one bucket as a single contiguous 48KB run. CAP=24 vs live
// bucket load lambda~10.5: Poisson tail -> a handful of spills device-wide,
// handled exactly via the overflow list. (R11 tried CAP=20 + issue-order
// changes: -5.5us regression; reverted to the verified R5 configuration.)
#define CAP 24
#define REC_PER_B (NBLK * CAP)        // 12288 uints per bucket
#define OVF_CAP 16384                 // overflow list capacity (huge margin)

// dynamic LDS layout for scatter (bytes)
#define L_ELEM  0                         // uint4  s_elem4[3125]   50000 B
#define L_TAB   50000                     // float4 s_tab[100]       1600 B (16B aligned)
#define L_CNT   (L_TAB + 1600)            // uint   s_cnt[NB]        1024 B
#define L_REC   (L_CNT + 1024)            // uint   s_rec[NB*CAP]   24576 B
#define LDS_BYTES (L_REC + NB * CAP * 4)  // = 77200 B; x2 = 154400 < 160 KiB/CU

// ---------------------------------------------------------------------------
// Prep: (a) per-node argmax -> 4-bit element idx, packed 2 nodes/byte;
// (b) 100-entry pair table; (c) zero the overflow counter.
// No big zeroing needed: scatter writes EVERY records slot (0 if empty).
// ---------------------------------------------------------------------------
__global__ __launch_bounds__(256) void prep_kernel(
    const float* __restrict__ node_attrs,
    const int* __restrict__ atomic_numbers,
    const float* __restrict__ covalent_radii,
    uint8_t* __restrict__ node_elem4,
    float4* __restrict__ pair_tab,
    unsigned int* __restrict__ ovf_cnt) {
  int i = blockIdx.x * 256 + threadIdx.x;   // byte index: nodes 2i, 2i+1

  if (blockIdx.x == 0) {
    if (threadIdx.x < N_PAIRS) {
      int t = threadIdx.x;
      int eu = t / N_ELEMS, ev = t % N_ELEMS;
      float Zuf = (float)atomic_numbers[eu];
      float Zvf = (float)atomic_numbers[ev];
      float a = 0.4543f * 0.529f / (powf(Zuf, 0.3f) + powf(Zvf, 0.3f));
      float rmax = covalent_radii[(int)Zuf] + covalent_radii[(int)Zvf];
      pair_tab[t] = make_float4(1.0f / a, 0.5f * 14.3996f * Zuf * Zvf,
                                rmax, 1.0f / rmax);
    }
    if (threadIdx.x == 0) *ovf_cnt = 0u;
  }

  if (i < N_ELEM4) {
    unsigned int packed = 0;
#pragma unroll
    for (int h = 0; h < 2; ++h) {
      int node = 2 * i + h;
      const float2* row = (const float2*)(node_attrs + (size_t)node * N_ELEMS);
      float best = -INFINITY;
      int bj = 0;
#pragma unroll
      for (int k = 0; k < 5; ++k) {
        float2 v = row[k];
        if (v.x > best) { best = v.x; bj = 2 * k; }
        if (v.y > best) { best = v.y; bj = 2 * k + 1; }
      }
      packed |= (unsigned int)bj << (h * 4);
    }
    node_elem4[i] = (uint8_t)packed;
  }
}

// ---------------------------------------------------------------------------
// Per-edge math. envelope(p=6): 1 - 28 r^6 + 48 r^7 - 21 r^8, masked x<r_max.
// Element indices from the nibble-packed LDS table. Division via v_rcp_f32
// (rel err ~2^-22, inside tolerance). Returns exactly 0.0f for dead
// (~57%) edges; live values strictly positive -> rec==0 only for empty slots.
// ---------------------------------------------------------------------------
__device__ __forceinline__ float edge_val(float xi, int u, int v,
                                          const uint8_t* s_elem4,
                                          const float4* s_tab) {
  int eu = (s_elem4[u >> 1] >> ((u & 1) * 4)) & 0xF;
  int ev = (s_elem4[v >> 1] >> ((v & 1) * 4)) & 0xF;
  float4 tb = s_tab[eu * N_ELEMS + ev];
  float roa = xi * tb.x;
  float phi = 0.1818f  * __expf(-3.2f    * roa)
            + 0.5099f  * __expf(-0.9423f * roa)
            + 0.2802f  * __expf(-0.4028f * roa)
            + 0.02817f * __expf(-0.2016f * roa);
  float val = tb.y * phi * __builtin_amdgcn_rcpf(xi);
  float r  = xi * tb.w;
  float r2 = r * r;
  float r6 = r2 * r2 * r2;
  float env = 1.0f - 28.0f * r6 + 48.0f * r6 * r - 21.0f * r6 * r2;
  return (xi < tb.z) ? val * env : 0.0f;
}

// ---------------------------------------------------------------------------
// Phase 2 (R25 = verbatim R5/R17, best measured 104.5us): ZERO O(E)
// scattered global lane-ops (R0-R3 paid ~1.4M at ~15-30cyc = the 35-65us
// gap; WRITE_SIZE=32B*live proved per-op write-through atomics).
//   - live edges ranked per bucket via LDS atomics (CU-local)
//   - staged in s_rec[256][24], dumped COALESCED (0 = empty slot)
//   - rank >= CAP (Poisson tail) -> exact overflow list
// record: fp32 value, low 9 mantissa bits replaced by local node id (<391).
// Later rounds' variations all lost: R9 fusion +barrier slack, R10 pass
// split neutral (TLP already hides gather latency), R11 issue-reorder/-CAP
// regressed (register pressure under the 64-VGPR cap).
// ---------------------------------------------------------------------------
__global__ __launch_bounds__(SCAT_THREADS) void scatter_kernel(
    const float* __restrict__ x,
    const int* __restrict__ edge_index,      // [2, E]
    const uint8_t* __restrict__ node_elem4,
    const float4* __restrict__ pair_tab,
    unsigned int* __restrict__ records,      // [NB][NBLK][CAP]
    unsigned int* __restrict__ ovf_cnt,
    uint2* __restrict__ ovf) {
  extern __shared__ char smem[];
  uint4*        s_elem4_v = (uint4*)(smem + L_ELEM);
  float4*       s_tab     = (float4*)(smem + L_TAB);
  unsigned int* s_cnt     = (unsigned int*)(smem + L_CNT);
  unsigned int* s_rec     = (unsigned int*)(smem + L_REC);
  const uint8_t* s_elem4  = (const uint8_t*)s_elem4_v;

  int tid = threadIdx.x;

  // stage packed element table (50 KB) + pair table, coalesced uint4 copies
  {
    const uint4* src = (const uint4*)node_elem4;
    for (int j = tid; j < N_ELEM4 / 16; j += SCAT_THREADS) s_elem4_v[j] = src[j];
  }
  if (tid < N_PAIRS) s_tab[tid] = pair_tab[tid];
  if (tid < NB) s_cnt[tid] = 0u;
  __syncthreads();

#pragma unroll
  for (int k = 0; k < 2; ++k) {
    int gl = k * SCAT_THREADS + tid;          // local float4-group (< 1564)
    int g  = blockIdx.x * NGROUPS + gl;       // global float4-group
    if (gl >= NGROUPS || g >= NG4) continue;
    int e = g * 4;
    float4 xv = *(const float4*)(x + e);
    int4 uu = *(const int4*)(edge_index + e);
    int4 vv = *(const int4*)(edge_index + N_EDGES + e);
    int ru[4] = {uu.x, uu.y, uu.z, uu.w};
    int rv[4] = {vv.x, vv.y, vv.z, vv.w};
    float xs[4] = {xv.x, xv.y, xv.z, xv.w};
#pragma unroll
    for (int c = 0; c < 4; ++c) {
      float v = edge_val(xs[c], ru[c], rv[c], s_elem4, s_tab);
      if (v != 0.0f) {                 // zero-skip: +0 never changes the sum
        unsigned int b = (unsigned int)rv[c] / NPB;
        unsigned int lid = (unsigned int)rv[c] - b * NPB;
        unsigned int r = atomicAdd(&s_cnt[b], 1u);     // LDS rank (CU-local)
        if (r < CAP) {
          s_rec[b * CAP + r] = (__float_as_uint(v) & ~0x1FFu) | lid;
        } else {                       // rare exact spill
          unsigned int idx = atomicAdd(ovf_cnt, 1u);
          if (idx < OVF_CAP)
            ovf[idx] = make_uint2(__float_as_uint(v), (unsigned int)rv[c]);
        }
      }
    }
  }
  __syncthreads();

  // coalesced dump: every (bucket,slot) written; empty slots = 0.
  for (int j = tid; j < NB * CAP; j += SCAT_THREADS) {
    int b = j / CAP, slot = j - b * CAP;
    unsigned int c = s_cnt[b]; if (c > CAP) c = CAP;
    unsigned int rec = ((unsigned int)slot < c) ? s_rec[j] : 0u;
    records[(size_t)b * REC_PER_B + (size_t)blockIdx.x * CAP + slot] = rec;
  }
}

// ---------------------------------------------------------------------------
// Phase 3: block b reads records[b] as ONE contiguous 48KB coalesced run
// (12 recs/thread), skips rec==0, LDS float atomics into 391 bins, then the
// tiny overflow list (filtered by bucket), coalesced store of every out
// element (no zeroing of the poisoned d_out needed).
// ---------------------------------------------------------------------------
__global__ __launch_bounds__(1024) void reduce_kernel(
    const unsigned int* __restrict__ records,
    const unsigned int* __restrict__ ovf_cnt,
    const uint2* __restrict__ ovf,
    float* __restrict__ out) {
  __shared__ float bins[NPB];
  int b = blockIdx.x, tid = threadIdx.x;

  if (tid < NPB) bins[tid] = 0.0f;
  __syncthreads();

  const unsigned int* rp = records + (size_t)b * REC_PER_B;
  for (int i = tid; i < REC_PER_B; i += 1024) {
    unsigned int rec = rp[i];
    if (rec != 0u)
      atomicAdd(&bins[rec & 0x1FFu], __uint_as_float(rec & ~0x1FFu));
  }

  unsigned int on = *ovf_cnt; if (on > OVF_CAP) on = OVF_CAP;
  for (unsigned int j = tid; j < on; j += 1024) {
    uint2 e2 = ovf[j];
    unsigned int nb = e2.y / NPB;
    if (nb == (unsigned int)b)
      atomicAdd(&bins[e2.y - nb * NPB], __uint_as_float(e2.x));
  }
  __syncthreads();

  int nb0 = b * NPB;
  if (tid < NPB && nb0 + tid < N_NODES) out[nb0 + tid] = bins[tid];
}

// ---------------------------------------------------------------------------
extern "C" void kernel_launch(void* const* d_in, const int* in_sizes, int n_in,
                              void* d_out, int out_size, void* d_ws, size_t ws_size,
                              hipStream_t stream) {
  const float* x              = (const float*)d_in[0];
  const float* node_attrs     = (const float*)d_in[1];
  const int*   edge_index     = (const int*)d_in[2];
  const int*   atomic_numbers = (const int*)d_in[3];
  const float* covalent_radii = (const float*)d_in[4];
  float* out = (float*)d_out;

  // ws layout (aligned sections):
  //   records    uint [NB*NBLK*CAP] = 12,582,912 B @ 0
  //   ovf_cnt    uint               =        16 B @ 12,582,912
  //   ovf        uint2[OVF_CAP]     =   131,072 B @ 12,582,928
  //   pair_tab   float4[100]        =     1,600 B @ 12,714,000
  //   node_elem4 uint8[N_ELEM4]     =    50,000 B @ 12,715,600
  char* wsp = (char*)d_ws;
  unsigned int* records    = (unsigned int*)wsp;
  unsigned int* ovf_cnt    = (unsigned int*)(wsp + 12582912);
  uint2*        ovf        = (uint2*)(wsp + 12582928);
  float4*       pair_tab   = (float4*)(wsp + 12714000);
  uint8_t*      node_elem4 = (uint8_t*)(wsp + 12715600);

  prep_kernel<<<PREP_BLOCKS, 256, 0, stream>>>(
      node_attrs, atomic_numbers, covalent_radii, node_elem4, pair_tab,
      ovf_cnt);

  scatter_kernel<<<NBLK, SCAT_THREADS, LDS_BYTES, stream>>>(
      x, edge_index, node_elem4, pair_tab, records, ovf_cnt, ovf);

  reduce_kernel<<<NB, 1024, 0, stream>>>(records, ovf_cnt, ovf, out);
}